// Round 1
// baseline (212.640 us; speedup 1.0000x reference)
//
#include <hip/hip_runtime.h>
#include <hip/hip_bf16.h>

#define DI __device__ __forceinline__

using f32x4 = __attribute__((ext_vector_type(4))) float;
using s16x8 = __attribute__((ext_vector_type(8))) short;
using u16x4 = __attribute__((ext_vector_type(4))) unsigned short;

DI unsigned short f2bf(float f) {
  union { float f; unsigned u; } v; v.f = f;
  unsigned r = v.u + 0x7FFFu + ((v.u >> 16) & 1u);   // RNE
  return (unsigned short)(r >> 16);
}

// ---------------- prep kernels ----------------
__global__ void k_cvt_x(const float* __restrict__ x, unsigned short* __restrict__ xb) {
  int i = (blockIdx.x * 256 + threadIdx.x) * 4;
  f32x4 v = *reinterpret_cast<const f32x4*>(x + i);
  u16x4 o;
  o[0] = f2bf(v[0]); o[1] = f2bf(v[1]); o[2] = f2bf(v[2]); o[3] = f2bf(v[3]);
  *reinterpret_cast<u16x4*>(xb + i) = o;
}

// Wt[w][n][h][k] = bf16(W_w[n][k][h])  -> B^T form, rows contiguous in k
__global__ void k_cvt_w(const float* __restrict__ wq, const float* __restrict__ wk,
                        const float* __restrict__ wv, unsigned short* __restrict__ Wt) {
  int o = blockIdx.x * 256 + threadIdx.x;           // 3*16*64*1024
  int k = o & 1023, h = (o >> 10) & 63, n = (o >> 16) & 15, w = o >> 20;
  const float* W = (w == 0) ? wq : (w == 1) ? wk : wv;
  Wt[o] = f2bf(W[(n * 1024 + k) * 64 + h]);
}

// Wot[d][k] = bf16(W_O[(n,h)=k][d])  (plain 1024x1024 transpose)
__global__ void k_cvt_wo(const float* __restrict__ wo, unsigned short* __restrict__ Wot) {
  int o = blockIdx.x * 256 + threadIdx.x;           // 1024*1024
  int k = o & 1023, d = o >> 10;
  Wot[o] = f2bf(wo[k * 1024 + d]);
}

// ---------------- GEMM: C[M,c] = A[M,K] * Bt[c,K]^T ----------------
// MODE 0: QKV projection (bias + 0.125 scale on Q, scatter to [b][n][p][h] bf16)
// MODE 1: output projection (bias b_O, fp32 out [m][c])
template <int MODE>
__launch_bounds__(256, 2)
__global__ void k_gemm(const unsigned short* __restrict__ A,
                       const unsigned short* __restrict__ Bt,
                       const float* __restrict__ bq, const float* __restrict__ bk,
                       const float* __restrict__ bv, const float* __restrict__ bo,
                       unsigned short* __restrict__ oq, unsigned short* __restrict__ ok_,
                       unsigned short* __restrict__ ov, float* __restrict__ of) {
  __shared__ __align__(16) unsigned short As[128 * 64];
  __shared__ __align__(16) unsigned short Bs[128 * 64];
  const int t = threadIdx.x;
  const int lane = t & 63, wid = t >> 6;
  const int wm = wid >> 1, wn = wid & 1;
  const int l15 = lane & 15, l4 = lane >> 4;
  const int m0 = blockIdx.y * 128, c0 = blockIdx.x * 128;

  f32x4 acc[4][4] = {};

  for (int k0 = 0; k0 < 1024; k0 += 64) {
    if (k0) __syncthreads();
#pragma unroll
    for (int i = 0; i < 4; ++i) {
      int idx = i * 256 + t;
      int r = idx >> 3, kb = idx & 7;
      int lo = r * 64 + (((kb * 16) ^ ((r & 7) << 4)) >> 1);   // swizzled ushort idx
      *reinterpret_cast<s16x8*>(&As[lo]) =
          *reinterpret_cast<const s16x8*>(A + (m0 + r) * 1024 + k0 + kb * 8);
      *reinterpret_cast<s16x8*>(&Bs[lo]) =
          *reinterpret_cast<const s16x8*>(Bt + (c0 + r) * 1024 + k0 + kb * 8);
    }
    __syncthreads();
    s16x8 af[4][2], bf[4][2];
#pragma unroll
    for (int mb = 0; mb < 4; ++mb) {
      int r = wm * 64 + mb * 16 + l15;
#pragma unroll
      for (int kc = 0; kc < 2; ++kc) {
        int byo = (kc * 64 + l4 * 16) ^ ((r & 7) << 4);
        af[mb][kc] = *reinterpret_cast<const s16x8*>(&As[r * 64 + (byo >> 1)]);
      }
    }
#pragma unroll
    for (int nb = 0; nb < 4; ++nb) {
      int r = wn * 64 + nb * 16 + l15;
#pragma unroll
      for (int kc = 0; kc < 2; ++kc) {
        int byo = (kc * 64 + l4 * 16) ^ ((r & 7) << 4);
        bf[nb][kc] = *reinterpret_cast<const s16x8*>(&Bs[r * 64 + (byo >> 1)]);
      }
    }
#pragma unroll
    for (int mb = 0; mb < 4; ++mb)
#pragma unroll
      for (int nb = 0; nb < 4; ++nb) {
        acc[mb][nb] = __builtin_amdgcn_mfma_f32_16x16x32_bf16(af[mb][0], bf[nb][0], acc[mb][nb], 0, 0, 0);
        acc[mb][nb] = __builtin_amdgcn_mfma_f32_16x16x32_bf16(af[mb][1], bf[nb][1], acc[mb][nb], 0, 0, 0);
      }
  }

#pragma unroll
  for (int mb = 0; mb < 4; ++mb) {
#pragma unroll
    for (int nb = 0; nb < 4; ++nb) {
      int c = c0 + wn * 64 + nb * 16 + l15;
#pragma unroll
      for (int r = 0; r < 4; ++r) {
        int m = m0 + wm * 64 + mb * 16 + l4 * 4 + r;
        float v = acc[mb][nb][r];
        if (MODE == 0) {
          int w = c >> 10, cc = c & 1023;
          const float* bias = (w == 0) ? bq : (w == 1) ? bk : bv;
          unsigned short* dst = (w == 0) ? oq : (w == 1) ? ok_ : ov;
          float scl = (w == 0) ? 0.125f : 1.0f;    // fold 1/sqrt(64) into Q
          int n = cc >> 6, h = cc & 63;
          int b = m >> 11, p = m & 2047;
          dst[((b * 16 + n) * 2048 + p) * 64 + h] = f2bf((v + bias[cc]) * scl);
        } else {
          of[m * 1024 + c] = v + bo[c];
        }
      }
    }
  }
}

// ---------------- flash attention (causal) ----------------
// grid (16 qtiles, 32 bn); 4 waves; wave w owns rows q0+16w and q0+64+16w
__launch_bounds__(256, 2)
__global__ void k_attn(const unsigned short* __restrict__ Q,
                       const unsigned short* __restrict__ K,
                       const unsigned short* __restrict__ V,
                       unsigned short* __restrict__ Z) {
  __shared__ __align__(16) unsigned short Ks[64 * 64];    // [k][h] swizzled
  __shared__ __align__(16) unsigned short Vt[64 * 64];    // [h][k] swizzled
  __shared__ __align__(16) unsigned short Ps[4 * 16 * 64];// per-wave P scratch
  const int t = threadIdx.x;
  const int lane = t & 63, wid = t >> 6;
  const int l15 = lane & 15, l4 = lane >> 4;
  const int bn = blockIdx.y, q0 = blockIdx.x * 128;
  const int b = bn >> 4, n = bn & 15;
  const unsigned short* Qb = Q + bn * (2048 * 64);
  const unsigned short* Kb = K + bn * (2048 * 64);
  const unsigned short* Vb = V + bn * (2048 * 64);
  const int g0 = q0 + wid * 16;
  const int g1 = q0 + 64 + wid * 16;
  const f32x4 fz = {};

  s16x8 qf[2][2];
#pragma unroll
  for (int mb = 0; mb < 2; ++mb) {
    int row = (mb ? g1 : g0) + l15;
#pragma unroll
    for (int kc = 0; kc < 2; ++kc)
      qf[mb][kc] = *reinterpret_cast<const s16x8*>(Qb + row * 64 + kc * 32 + l4 * 8);
  }

  f32x4 o[2][4] = {};
  float mrun[2][4], lrun[2][4];
#pragma unroll
  for (int mb = 0; mb < 2; ++mb)
#pragma unroll
    for (int r = 0; r < 4; ++r) { mrun[mb][r] = -1e30f; lrun[mb][r] = 0.f; }

  unsigned short* Pw = Ps + wid * (16 * 64);
  const int nkt = (q0 + 128) >> 6;

  for (int kt = 0; kt < nkt; ++kt) {
    const int k0 = kt << 6;
    if (kt) __syncthreads();
#pragma unroll
    for (int i = 0; i < 2; ++i) {
      int idx = i * 256 + t;
      int r = idx >> 3, kb = idx & 7;
      s16x8 vk = *reinterpret_cast<const s16x8*>(Kb + (k0 + r) * 64 + kb * 8);
      *reinterpret_cast<s16x8*>(&Ks[r * 64 + (((kb * 16) ^ ((r & 7) << 4)) >> 1)]) = vk;
      s16x8 vv = *reinterpret_cast<const s16x8*>(Vb + (k0 + r) * 64 + kb * 8);
#pragma unroll
      for (int j = 0; j < 8; ++j) {
        int h = kb * 8 + j;
        Vt[h * 64 + (((r * 2) ^ ((h & 7) << 4)) >> 1)] = (unsigned short)vv[j];
      }
    }
    __syncthreads();

    s16x8 kf[4][2], vf[4][2];
#pragma unroll
    for (int kb2 = 0; kb2 < 4; ++kb2) {
      int r = kb2 * 16 + l15;
#pragma unroll
      for (int kc = 0; kc < 2; ++kc) {
        int byo = (kc * 64 + l4 * 16) ^ ((r & 7) << 4);
        kf[kb2][kc] = *reinterpret_cast<const s16x8*>(&Ks[r * 64 + (byo >> 1)]);
        vf[kb2][kc] = *reinterpret_cast<const s16x8*>(&Vt[r * 64 + (byo >> 1)]);
      }
    }

#pragma unroll
    for (int mb = 0; mb < 2; ++mb) {
      const int g = mb ? g1 : g0;
      if (k0 > g + 15) continue;                 // tile fully above diagonal for this group
      f32x4 s[4];
#pragma unroll
      for (int kb2 = 0; kb2 < 4; ++kb2) {
        s[kb2] = __builtin_amdgcn_mfma_f32_16x16x32_bf16(qf[mb][0], kf[kb2][0], fz, 0, 0, 0);
        s[kb2] = __builtin_amdgcn_mfma_f32_16x16x32_bf16(qf[mb][1], kf[kb2][1], s[kb2], 0, 0, 0);
      }
      if (k0 + 63 > g) {                         // diagonal tile: mask k > q
#pragma unroll
        for (int kb2 = 0; kb2 < 4; ++kb2)
#pragma unroll
          for (int r = 0; r < 4; ++r) {
            int kcol = k0 + kb2 * 16 + l15;
            int qrow = g + l4 * 4 + r;
            if (kcol > qrow) s[kb2][r] = -1e30f;
          }
      }
      float rm[4], mnew[4], scl[4], rs[4];
#pragma unroll
      for (int r = 0; r < 4; ++r)
        rm[r] = fmaxf(fmaxf(s[0][r], s[1][r]), fmaxf(s[2][r], s[3][r]));
#pragma unroll
      for (int off = 1; off < 16; off <<= 1)
#pragma unroll
        for (int r = 0; r < 4; ++r) rm[r] = fmaxf(rm[r], __shfl_xor(rm[r], off));
      f32x4 pv4[4];
#pragma unroll
      for (int r = 0; r < 4; ++r) {
        mnew[r] = fmaxf(mrun[mb][r], rm[r]);
        scl[r] = __expf(mrun[mb][r] - mnew[r]);
        rs[r] = 0.f;
      }
#pragma unroll
      for (int kb2 = 0; kb2 < 4; ++kb2)
#pragma unroll
        for (int r = 0; r < 4; ++r) {
          float e = __expf(s[kb2][r] - mnew[r]);
          pv4[kb2][r] = e;
          rs[r] += e;
        }
#pragma unroll
      for (int off = 1; off < 16; off <<= 1)
#pragma unroll
        for (int r = 0; r < 4; ++r) rs[r] += __shfl_xor(rs[r], off);
#pragma unroll
      for (int r = 0; r < 4; ++r) {
        lrun[mb][r] = lrun[mb][r] * scl[r] + rs[r];
        mrun[mb][r] = mnew[r];
      }
#pragma unroll
      for (int hb = 0; hb < 4; ++hb)
#pragma unroll
        for (int r = 0; r < 4; ++r) o[mb][hb][r] *= scl[r];

      // P (D-layout) -> per-wave LDS -> A-frag layout; no barrier (wave-private)
#pragma unroll
      for (int kb2 = 0; kb2 < 4; ++kb2)
#pragma unroll
        for (int r = 0; r < 4; ++r) {
          int ql = l4 * 4 + r, kk = kb2 * 16 + l15;
          Pw[ql * 64 + (((kk * 2) ^ ((ql & 7) << 4)) >> 1)] = f2bf(pv4[kb2][r]);
        }
      s16x8 pa[2];
#pragma unroll
      for (int kc = 0; kc < 2; ++kc) {
        int byo = (kc * 64 + l4 * 16) ^ ((l15 & 7) << 4);
        pa[kc] = *reinterpret_cast<const s16x8*>(&Pw[l15 * 64 + (byo >> 1)]);
      }
#pragma unroll
      for (int hb = 0; hb < 4; ++hb) {
        o[mb][hb] = __builtin_amdgcn_mfma_f32_16x16x32_bf16(pa[0], vf[hb][0], o[mb][hb], 0, 0, 0);
        o[mb][hb] = __builtin_amdgcn_mfma_f32_16x16x32_bf16(pa[1], vf[hb][1], o[mb][hb], 0, 0, 0);
      }
    }
  }

#pragma unroll
  for (int mb = 0; mb < 2; ++mb) {
    const int g = mb ? g1 : g0;
#pragma unroll
    for (int hb = 0; hb < 4; ++hb)
#pragma unroll
      for (int r = 0; r < 4; ++r) {
        int qrow = g + l4 * 4 + r;
        int h = hb * 16 + l15;
        float val = o[mb][hb][r] / lrun[mb][r];
        Z[(b * 2048 + qrow) * 1024 + n * 64 + h] = f2bf(val);
      }
  }
}

// ---------------- launcher ----------------
extern "C" void kernel_launch(void* const* d_in, const int* in_sizes, int n_in,
                              void* d_out, int out_size, void* d_ws, size_t ws_size,
                              hipStream_t stream) {
  const float* x  = (const float*)d_in[0];
  const float* wq = (const float*)d_in[1];
  const float* wk = (const float*)d_in[2];
  const float* wv = (const float*)d_in[3];
  const float* wo = (const float*)d_in[4];
  const float* bq = (const float*)d_in[5];
  const float* bk = (const float*)d_in[6];
  const float* bv = (const float*)d_in[7];
  const float* bo = (const float*)d_in[8];
  char* ws = (char*)d_ws;
  unsigned short* xb  = (unsigned short*)(ws);                  // 8 MiB  [4096][1024]
  unsigned short* Wt  = (unsigned short*)(ws + (8  << 20));     // 6 MiB  [3][16][64][1024]
  unsigned short* Wot = (unsigned short*)(ws + (14 << 20));     // 2 MiB  [1024][1024]
  unsigned short* Qw  = (unsigned short*)(ws + (16 << 20));     // 8 MiB  [2][16][2048][64]
  unsigned short* Kw  = (unsigned short*)(ws + (24 << 20));     // 8 MiB
  unsigned short* Vw  = (unsigned short*)(ws + (32 << 20));     // 8 MiB
  unsigned short* Zw  = (unsigned short*)(ws + (40 << 20));     // 8 MiB  [4096][1024]
  float* out = (float*)d_out;

  k_cvt_x <<<4096,  256, 0, stream>>>(x, xb);
  k_cvt_w <<<12288, 256, 0, stream>>>(wq, wk, wv, Wt);
  k_cvt_wo<<<4096,  256, 0, stream>>>(wo, Wot);
  k_gemm<0><<<dim3(24, 32), 256, 0, stream>>>(xb, Wt, bq, bk, bv, nullptr, Qw, Kw, Vw, nullptr);
  k_attn   <<<dim3(16, 32), 256, 0, stream>>>(Qw, Kw, Vw, Zw);
  k_gemm<1><<<dim3(8, 32),  256, 0, stream>>>(Zw, Wot, nullptr, nullptr, nullptr, bo,
                                              nullptr, nullptr, nullptr, out);
}

// Round 2
// 141.317 us; speedup vs baseline: 1.5047x; 1.5047x over previous
//
#include <hip/hip_runtime.h>
#include <hip/hip_bf16.h>

#define DI __device__ __forceinline__

using f32x4  = __attribute__((ext_vector_type(4)))  float;
using f32x16 = __attribute__((ext_vector_type(16))) float;
using s16x8  = __attribute__((ext_vector_type(8)))  short;
using s32x4  = __attribute__((ext_vector_type(4)))  int;
using u16x4  = __attribute__((ext_vector_type(4)))  unsigned short;
using u32x4  = __attribute__((ext_vector_type(4)))  unsigned;

DI unsigned short f2bf(float f) {
  union { float f; unsigned u; } v; v.f = f;
  unsigned r = v.u + 0x7FFFu + ((v.u >> 16) & 1u);   // RNE
  return (unsigned short)(r >> 16);
}

DI unsigned cvtpk(float lo, float hi) {
  unsigned d;
  asm("v_cvt_pk_bf16_f32 %0, %1, %2" : "=v"(d) : "v"(lo), "v"(hi));
  return d;
}
DI void pswap(unsigned &a, unsigned &b) {
  asm("v_permlane32_swap_b32 %0, %1" : "+v"(a), "+v"(b));
}

// ---------------- prep kernels ----------------
__global__ void k_cvt_x(const float* __restrict__ x, unsigned short* __restrict__ xb) {
  int i = (blockIdx.x * 256 + threadIdx.x) * 4;
  f32x4 v = *reinterpret_cast<const f32x4*>(x + i);
  u16x4 o;
  o[0] = f2bf(v[0]); o[1] = f2bf(v[1]); o[2] = f2bf(v[2]); o[3] = f2bf(v[3]);
  *reinterpret_cast<u16x4*>(xb + i) = o;
}

// Wt[w][n][h][k] = bf16(W_w[n][k][h])  -> B^T form, rows contiguous in k
__global__ void k_cvt_w(const float* __restrict__ wq, const float* __restrict__ wk,
                        const float* __restrict__ wv, unsigned short* __restrict__ Wt) {
  int o = blockIdx.x * 256 + threadIdx.x;           // 3*16*64*1024
  int k = o & 1023, h = (o >> 10) & 63, n = (o >> 16) & 15, w = o >> 20;
  const float* W = (w == 0) ? wq : (w == 1) ? wk : wv;
  Wt[o] = f2bf(W[(n * 1024 + k) * 64 + h]);
}

// Wot[d][k] = bf16(W_O[(n,h)=k][d])
__global__ void k_cvt_wo(const float* __restrict__ wo, unsigned short* __restrict__ Wot) {
  int o = blockIdx.x * 256 + threadIdx.x;           // 1024*1024
  int k = o & 1023, d = o >> 10;
  Wot[o] = f2bf(wo[k * 1024 + d]);
}

// ---------------- GEMM: C[M,c] = A[M,K] * Bt[c,K]^T ----------------
// MODE 0: QKV proj (bias; 0.125 scale on Q; Q,K -> [b][n][p][h]; V -> [b][n][h][p])
// MODE 1: output proj (bias b_O, fp32 out [m][c])
template <int MODE>
__launch_bounds__(256, 2)
__global__ void k_gemm(const unsigned short* __restrict__ A,
                       const unsigned short* __restrict__ Bt,
                       const float* __restrict__ bq, const float* __restrict__ bk,
                       const float* __restrict__ bv, const float* __restrict__ bo,
                       unsigned short* __restrict__ oq, unsigned short* __restrict__ ok_,
                       unsigned short* __restrict__ ov, float* __restrict__ of) {
  __shared__ __align__(16) unsigned short As[128 * 64];
  __shared__ __align__(16) unsigned short Bs[128 * 64];
  const int t = threadIdx.x;
  const int lane = t & 63, wid = t >> 6;
  const int wm = wid >> 1, wn = wid & 1;
  const int l15 = lane & 15, l4 = lane >> 4;
  const int m0 = blockIdx.y * 128, c0 = blockIdx.x * 128;

  f32x4 acc[4][4] = {};

  for (int k0 = 0; k0 < 1024; k0 += 64) {
    if (k0) __syncthreads();
#pragma unroll
    for (int i = 0; i < 4; ++i) {
      int idx = i * 256 + t;
      int r = idx >> 3, kb = idx & 7;
      int lo = r * 64 + (((kb * 16) ^ ((r & 7) << 4)) >> 1);
      *reinterpret_cast<s16x8*>(&As[lo]) =
          *reinterpret_cast<const s16x8*>(A + (m0 + r) * 1024 + k0 + kb * 8);
      *reinterpret_cast<s16x8*>(&Bs[lo]) =
          *reinterpret_cast<const s16x8*>(Bt + (c0 + r) * 1024 + k0 + kb * 8);
    }
    __syncthreads();
    s16x8 af[4][2], bf[4][2];
#pragma unroll
    for (int mb = 0; mb < 4; ++mb) {
      int r = wm * 64 + mb * 16 + l15;
#pragma unroll
      for (int kc = 0; kc < 2; ++kc) {
        int byo = (kc * 64 + l4 * 16) ^ ((r & 7) << 4);
        af[mb][kc] = *reinterpret_cast<const s16x8*>(&As[r * 64 + (byo >> 1)]);
      }
    }
#pragma unroll
    for (int nb = 0; nb < 4; ++nb) {
      int r = wn * 64 + nb * 16 + l15;
#pragma unroll
      for (int kc = 0; kc < 2; ++kc) {
        int byo = (kc * 64 + l4 * 16) ^ ((r & 7) << 4);
        bf[nb][kc] = *reinterpret_cast<const s16x8*>(&Bs[r * 64 + (byo >> 1)]);
      }
    }
#pragma unroll
    for (int mb = 0; mb < 4; ++mb)
#pragma unroll
      for (int nb = 0; nb < 4; ++nb) {
        acc[mb][nb] = __builtin_amdgcn_mfma_f32_16x16x32_bf16(af[mb][0], bf[nb][0], acc[mb][nb], 0, 0, 0);
        acc[mb][nb] = __builtin_amdgcn_mfma_f32_16x16x32_bf16(af[mb][1], bf[nb][1], acc[mb][nb], 0, 0, 0);
      }
  }

#pragma unroll
  for (int mb = 0; mb < 4; ++mb) {
#pragma unroll
    for (int nb = 0; nb < 4; ++nb) {
      int c = c0 + wn * 64 + nb * 16 + l15;
      int mbase = m0 + wm * 64 + mb * 16 + l4 * 4;
      if (MODE == 0) {
        int w = c >> 10, cc = c & 1023;
        int nH = cc >> 6, h = cc & 63;
        const float* bias = (w == 0) ? bq : (w == 1) ? bk : bv;
        float bval = bias[cc];
        if (w == 2) {                       // V -> transposed [b][n][h][p]
          int bb = mbase >> 11, p = mbase & 2047;
          u16x4 pk4;
#pragma unroll
          for (int r = 0; r < 4; ++r) pk4[r] = f2bf(acc[mb][nb][r] + bval);
          *reinterpret_cast<u16x4*>(ov + (((long)bb * 16 + nH) * 64 + h) * 2048 + p) = pk4;
        } else {
          unsigned short* dst = (w == 0) ? oq : ok_;
          float scl = (w == 0) ? 0.125f : 1.0f;   // fold 1/sqrt(64) into Q
#pragma unroll
          for (int r = 0; r < 4; ++r) {
            int m = mbase + r;
            int bb = m >> 11, p = m & 2047;
            dst[(((long)bb * 16 + nH) * 2048 + p) * 64 + h] = f2bf((acc[mb][nb][r] + bval) * scl);
          }
        }
      } else {
#pragma unroll
        for (int r = 0; r < 4; ++r) of[(long)(mbase + r) * 1024 + c] = acc[mb][nb][r] + bo[c];
      }
    }
  }
}

// ---------------- flash attention (causal), 32x32 swapped layout ----------------
// block: 2 waves x 32 q-rows; grid (32 qtiles reversed, 32 bn)
__launch_bounds__(128, 2)
__global__ void k_attn(const unsigned short* __restrict__ Q,
                       const unsigned short* __restrict__ K,
                       const unsigned short* __restrict__ VT,
                       unsigned short* __restrict__ Z) {
  __shared__ __align__(16) unsigned short Ks[64 * 64];   // [k][h] swizzled
  __shared__ __align__(16) unsigned short Vs[64 * 64];   // [h][k] swizzled (from VT)
  __shared__ unsigned Zl[2][32 * 33];                    // per-wave O transpose buffer
  const int t = threadIdx.x;
  const int lane = t & 63, wv = t >> 6;
  const int l31 = lane & 31, h5 = lane >> 5;
  const int qtb = 31 - (int)blockIdx.x;                  // heavy tiles first
  const int bn = blockIdx.y;
  const int b = bn >> 4, n = bn & 15;
  const int q0 = qtb * 64;
  const int q0w = q0 + wv * 32;
  const int qq = q0w + l31;                              // this lane's q row
  const unsigned short* Qb = Q + (long)bn * (2048 * 64);
  const unsigned short* Kb = K + (long)bn * (2048 * 64);
  const unsigned short* Vb = VT + (long)bn * (64 * 2048);

  s16x8 qf[4];
#pragma unroll
  for (int hc = 0; hc < 4; ++hc)
    qf[hc] = *reinterpret_cast<const s16x8*>(Qb + qq * 64 + hc * 16 + h5 * 8);

  f32x16 o0 = {}, o1 = {};                               // O^T[h][q]
  float mrun = -1e30f, lrun = 0.f;

  const int nkt = qtb + 1;
  const int rr = t >> 3, kb = t & 7;
  const int sw = ((kb * 16) ^ ((rr & 7) << 4)) >> 1;     // swizzled ushort offset
  const int swl = ((l31 & 7) << 4);

  s16x8 kreg[4], vreg[4];
#pragma unroll
  for (int i = 0; i < 4; ++i) {                          // prologue loads (kt=0)
    int r = i * 16 + rr;
    kreg[i] = *reinterpret_cast<const s16x8*>(Kb + r * 64 + kb * 8);
    vreg[i] = *reinterpret_cast<const s16x8*>(Vb + r * 2048 + kb * 8);
  }

  for (int kt = 0; kt < nkt; ++kt) {
    const int k0 = kt << 6;
    __syncthreads();                                     // prev compute done
#pragma unroll
    for (int i = 0; i < 4; ++i) {
      int r = i * 16 + rr;
      *reinterpret_cast<s16x8*>(&Ks[r * 64 + sw]) = kreg[i];
      *reinterpret_cast<s16x8*>(&Vs[r * 64 + sw]) = vreg[i];
    }
    __syncthreads();
    if (kt + 1 < nkt) {                                  // prefetch next tile
      const int k1 = k0 + 64;
#pragma unroll
      for (int i = 0; i < 4; ++i) {
        int r = i * 16 + rr;
        kreg[i] = *reinterpret_cast<const s16x8*>(Kb + (k1 + r) * 64 + kb * 8);
        vreg[i] = *reinterpret_cast<const s16x8*>(Vb + r * 2048 + k1 + kb * 8);
      }
    }

    // S^T = K . Q^T : D[k_local][q]
    f32x16 s0v = {}, s1v = {};
#pragma unroll
    for (int hc = 0; hc < 4; ++hc) {
      int cb = hc * 32 + h5 * 16;
      s16x8 kf0 = *reinterpret_cast<const s16x8*>(&Ks[l31 * 64 + ((cb ^ swl) >> 1)]);
      s16x8 kf1 = *reinterpret_cast<const s16x8*>(&Ks[(32 + l31) * 64 + ((cb ^ swl) >> 1)]);
      s0v = __builtin_amdgcn_mfma_f32_32x32x16_bf16(kf0, qf[hc], s0v, 0, 0, 0);
      s1v = __builtin_amdgcn_mfma_f32_32x32x16_bf16(kf1, qf[hc], s1v, 0, 0, 0);
    }

    if (k0 + 63 > q0w) {                                 // diagonal region: mask k > q
#pragma unroll
      for (int r = 0; r < 16; ++r) {
        int kA = k0 + (r & 3) + 8 * (r >> 2) + 4 * h5;
        if (kA > qq) s0v[r] = -1e30f;
        if (kA + 32 > qq) s1v[r] = -1e30f;
      }
    }

    float pmax = s0v[0];
#pragma unroll
    for (int r = 1; r < 16; ++r) pmax = fmaxf(pmax, s0v[r]);
#pragma unroll
    for (int r = 0; r < 16; ++r) pmax = fmaxf(pmax, s1v[r]);
    pmax = fmaxf(pmax, __shfl_xor(pmax, 32));

    if (__any(pmax > mrun + 8.f)) {                      // defer-max (T13)
      float mnew = fmaxf(mrun, pmax);
      float scl = __expf(mrun - mnew);
      lrun *= scl;
#pragma unroll
      for (int r = 0; r < 16; ++r) { o0[r] *= scl; o1[r] *= scl; }
      mrun = mnew;
    }
    float rs = 0.f;
#pragma unroll
    for (int r = 0; r < 16; ++r) { s0v[r] = __expf(s0v[r] - mrun); rs += s0v[r]; }
#pragma unroll
    for (int r = 0; r < 16; ++r) { s1v[r] = __expf(s1v[r] - mrun); rs += s1v[r]; }
    rs += __shfl_xor(rs, 32);
    lrun += rs;

    // P -> bf16 B-frags via cvt_pk + permlane32_swap (T12)
    unsigned PK0[8], PK1[8];
#pragma unroll
    for (int m2 = 0; m2 < 8; ++m2) {
      PK0[m2] = cvtpk(s0v[2 * m2], s0v[2 * m2 + 1]);
      PK1[m2] = cvtpk(s1v[2 * m2], s1v[2 * m2 + 1]);
    }
    s16x8 pb[4];
#pragma unroll
    for (int c = 0; c < 4; ++c) {
      int base = (c & 1) * 4;
      unsigned x0 = (c >> 1) ? PK1[base + 0] : PK0[base + 0];
      unsigned y0 = (c >> 1) ? PK1[base + 2] : PK0[base + 2];
      unsigned x1 = (c >> 1) ? PK1[base + 1] : PK0[base + 1];
      unsigned y1 = (c >> 1) ? PK1[base + 3] : PK0[base + 3];
      pswap(x0, y0);
      pswap(x1, y1);
      union { s32x4 i; s16x8 h; } u;
      u.i = s32x4{(int)x0, (int)x1, (int)y0, (int)y1};
      pb[c] = u.h;
    }

    // O^T += V^T . P^T : D[h][q]
#pragma unroll
    for (int hb = 0; hb < 2; ++hb) {
      int row = hb * 32 + l31;
#pragma unroll
      for (int c = 0; c < 4; ++c) {
        int cbv = c * 32 + h5 * 16;
        s16x8 vf = *reinterpret_cast<const s16x8*>(&Vs[row * 64 + ((cbv ^ swl) >> 1)]);
        if (hb == 0) o0 = __builtin_amdgcn_mfma_f32_32x32x16_bf16(vf, pb[c], o0, 0, 0, 0);
        else         o1 = __builtin_amdgcn_mfma_f32_32x32x16_bf16(vf, pb[c], o1, 0, 0, 0);
      }
    }
  }

  // epilogue: normalize, transpose O^T->O through LDS, coalesced store
  float inv = 1.0f / lrun;
#pragma unroll
  for (int hb = 0; hb < 2; ++hb) {
#pragma unroll
    for (int rp = 0; rp < 8; ++rp) {
      float vlo = (hb ? o1[2 * rp] : o0[2 * rp]) * inv;
      float vhi = (hb ? o1[2 * rp + 1] : o0[2 * rp + 1]) * inv;
      unsigned d = cvtpk(vlo, vhi);
      int col = 16 * hb + 4 * (rp >> 1) + 2 * h5 + (rp & 1);
      Zl[wv][l31 * 33 + col] = d;
    }
  }
  asm volatile("s_waitcnt lgkmcnt(0)" ::: "memory");     // wave-local LDS ordering
  const int qr = lane >> 1, cbs = (lane & 1) * 16;
  const long zb = ((long)(b * 2048 + q0w + qr)) * 512 + n * 32;  // dword index
  unsigned* Zd = (unsigned*)Z;
#pragma unroll
  for (int c2 = 0; c2 < 4; ++c2) {
    u32x4 w4;
#pragma unroll
    for (int i2 = 0; i2 < 4; ++i2) w4[i2] = Zl[wv][qr * 33 + cbs + 4 * c2 + i2];
    *reinterpret_cast<u32x4*>(Zd + zb + cbs + 4 * c2) = w4;
  }
}

// ---------------- launcher ----------------
extern "C" void kernel_launch(void* const* d_in, const int* in_sizes, int n_in,
                              void* d_out, int out_size, void* d_ws, size_t ws_size,
                              hipStream_t stream) {
  const float* x  = (const float*)d_in[0];
  const float* wq = (const float*)d_in[1];
  const float* wk = (const float*)d_in[2];
  const float* wv = (const float*)d_in[3];
  const float* wo = (const float*)d_in[4];
  const float* bq = (const float*)d_in[5];
  const float* bk = (const float*)d_in[6];
  const float* bv = (const float*)d_in[7];
  const float* bo = (const float*)d_in[8];
  char* ws = (char*)d_ws;
  unsigned short* xb  = (unsigned short*)(ws);                  // 8 MiB  [4096][1024]
  unsigned short* Wt  = (unsigned short*)(ws + (8  << 20));     // 6 MiB  [3][16][64][1024]
  unsigned short* Wot = (unsigned short*)(ws + (14 << 20));     // 2 MiB  [1024][1024]
  unsigned short* Qw  = (unsigned short*)(ws + (16 << 20));     // 8 MiB  [2][16][2048][64]
  unsigned short* Kw  = (unsigned short*)(ws + (24 << 20));     // 8 MiB  [2][16][2048][64]
  unsigned short* Vw  = (unsigned short*)(ws + (32 << 20));     // 8 MiB  [2][16][64][2048] (V^T)
  unsigned short* Zw  = (unsigned short*)(ws + (40 << 20));     // 8 MiB  [4096][1024]
  float* out = (float*)d_out;

  k_cvt_x <<<4096,  256, 0, stream>>>(x, xb);
  k_cvt_w <<<12288, 256, 0, stream>>>(wq, wk, wv, Wt);
  k_cvt_wo<<<4096,  256, 0, stream>>>(wo, Wot);
  k_gemm<0><<<dim3(24, 32), 256, 0, stream>>>(xb, Wt, bq, bk, bv, nullptr, Qw, Kw, Vw, nullptr);
  k_attn   <<<dim3(32, 32), 128, 0, stream>>>(Qw, Kw, Vw, Zw);
  k_gemm<1><<<dim3(8, 32),  256, 0, stream>>>(Zw, Wot, nullptr, nullptr, nullptr, bo,
                                              nullptr, nullptr, nullptr, out);
}